// Round 1
// 662.443 us; speedup vs baseline: 1.0350x; 1.0350x over previous
//
#include <hip/hip_runtime.h>
#include <hip/hip_bf16.h>

// Problem constants
#define H       4096
#define BS      819        // diagonal block size
#define NB      5          // full diagonal blocks; o=h=4095 handled separately
#define KPAD    832        // K per block padded to 26*32
#define NPADW   896        // packed-W rows per block (rows 819..895 are zeros)
#define M_TOTAL 16384      // 8 * 2048
#define XB_LD   (NB * KPAD) // 4160 bf16 per packed-x row
#define NT      (KPAD / 32) // 26 K-tiles of BK=32
#define BM      256
#define BN      256

typedef __bf16 bf16x8 __attribute__((ext_vector_type(8)));
typedef float  f32x4  __attribute__((ext_vector_type(4)));
typedef float  f32x4u __attribute__((ext_vector_type(4), aligned(4))); // dword-aligned vector load

__device__ __forceinline__ void gld_lds16(const void* gptr, void* ldsptr) {
    __builtin_amdgcn_global_load_lds(
        (const __attribute__((address_space(1))) void*)gptr,
        (__attribute__((address_space(3))) void*)ldsptr,
        16, 0, 0);
}

// ---------------------------------------------------------------------------
// Fused prep: pack_x (8 cols/thread, 16B stores) + pack_w + last_col in ONE
// launch (removes 2 serialized launches; pack_w/last_col hide under pack_x).
// ---------------------------------------------------------------------------
#define PX_GX     3                           // blocks.x per row (3*256 >= 520 chunks)
#define PX_BLOCKS (PX_GX * M_TOTAL)           // 49152
#define PW_PER_G  ((NPADW * KPAD) / 4 / 256)  // 728 blocks per diag block
#define PW_BLOCKS (PW_PER_G * NB)             // 3640
#define LC_BLOCKS (M_TOTAL / 256)             // 64

__global__ void prep_kernel(const float* __restrict__ x,
                            const float* __restrict__ W,
                            __hip_bfloat16* __restrict__ xb,
                            __hip_bfloat16* __restrict__ wb,
                            float* __restrict__ out) {
    const int bid = blockIdx.x;
    if (bid < PX_BLOCKS) {
        // ---- pack x: fp32 [M][4096] -> bf16 [M][5*832], zero pad 819..831 ----
        const int m  = bid / PX_GX;
        const int c8 = (bid % PX_GX) * 256 + threadIdx.x;
        if (c8 >= XB_LD / 8) return;          // 520 chunks of 8 per row
        const int j8 = c8 * 8;
        const int g  = j8 / KPAD;             // 832 % 8 == 0: no g-crossing
        const int jj = j8 - g * KPAD;
        const float* xr = x + (size_t)m * H + g * BS;
        union { __hip_bfloat16 h[8]; uint4 u; } v;
        if (jj + 8 <= BS) {
            // x offset g*819*4 is only 4B-aligned for odd g -> align(4) loads
            f32x4u f0 = *reinterpret_cast<const f32x4u*>(xr + jj);
            f32x4u f1 = *reinterpret_cast<const f32x4u*>(xr + jj + 4);
#pragma unroll
            for (int i = 0; i < 4; ++i) {
                v.h[i]     = __float2bfloat16(f0[i]);
                v.h[4 + i] = __float2bfloat16(f1[i]);
            }
        } else {
#pragma unroll
            for (int i = 0; i < 8; ++i) {
                float f = (jj + i < BS) ? xr[jj + i] : 0.f;
                v.h[i] = __float2bfloat16(f);
            }
        }
        *reinterpret_cast<uint4*>(xb + (size_t)m * XB_LD + j8) = v.u;  // 16B aligned
    } else if (bid < PX_BLOCKS + PW_BLOCKS) {
        // ---- pack W block-diagonal -> bf16 [5][896][832], zero-padded ----
        const int b   = bid - PX_BLOCKS;
        const int g   = b / PW_PER_G;
        const int t4  = (b - g * PW_PER_G) * 256 + threadIdx.x;
        const int idx = t4 * 4;
        const int n = idx / KPAD;
        const int k = idx - n * KPAD;         // multiple of 4
        union { __hip_bfloat16 h[4]; uint2 u; } v;
        if (n < BS && k + 4 <= BS) {
            f32x4u f = *reinterpret_cast<const f32x4u*>(W + (size_t)(g * BS + n) * H + g * BS + k);
#pragma unroll
            for (int i = 0; i < 4; ++i) v.h[i] = __float2bfloat16(f[i]);
        } else {
#pragma unroll
            for (int i = 0; i < 4; ++i) {
                float f = 0.f;
                if (n < BS && k + i < BS) f = W[(size_t)(g * BS + n) * H + g * BS + k + i];
                v.h[i] = __float2bfloat16(f);
            }
        }
        *reinterpret_cast<uint2*>(wb + ((size_t)g * NPADW + n) * KPAD + k) = v.u;
    } else {
        // ---- singleton block: out[:,4095] = x[:,4095] * W[4095,4095] ----
        const int m = (bid - PX_BLOCKS - PW_BLOCKS) * 256 + threadIdx.x;
        if (m >= M_TOTAL) return;
        const float w = W[(size_t)4095 * H + 4095];
        out[(size_t)m * H + 4095] = x[(size_t)m * H + 4095] * w;
    }
}

// ---------------------------------------------------------------------------
// Block-diagonal bf16 GEMM, deep-pipelined:
//   256x256 tile, 512 threads = 8 waves (2M x 4N), wave-tile 128x64
//   (8x4 frags of 16x16x32), BK=32, 4-buffer LDS ring (128 KiB),
//   counted s_waitcnt vmcnt(8) + raw s_barrier (1/tile, never drain-0),
//   XOR-swizzled LDS via pre-swizzled global_load_lds source (both-sides).
// ---------------------------------------------------------------------------
__global__ __launch_bounds__(512, 2)
void gemm_kernel(const __hip_bfloat16* __restrict__ xb,
                 const __hip_bfloat16* __restrict__ wb,
                 float* __restrict__ out) {
    __shared__ __hip_bfloat16 sA[4][BM * 32];   // 4 x 16 KB
    __shared__ __hip_bfloat16 sB[4][BN * 32];   // 4 x 16 KB  -> 128 KiB total

    const int tid  = threadIdx.x;
    const int lane = tid & 63;
    const int wid  = tid >> 6;        // 0..7
    const int wr   = wid >> 2;        // 0..1: wave row (128 rows each)
    const int wc   = wid & 3;         // 0..3: wave col (64 cols each)
    const int l16  = lane & 15;
    const int quad = lane >> 4;

    const int mBase = blockIdx.x * BM;
    const int nBase = blockIdx.y * BN;
    const int g     = blockIdx.z;

    // Staging: per tile, A = 16KB (2 units of 512x16B), B = 16KB (2 units).
    // LDS linear dest: byte L*16 -> row = L>>2, chunk c = L&3 (rows are 64B).
    // Swizzle: LDS chunk c holds global chunk kc = c ^ ((row>>1)&3)
    //   -> pre-swizzle the SOURCE address (gld_lds dest must stay linear).
    const int r0 = tid >> 2;                          // unit-0 row; unit-1 = +128
    const int kc = (tid & 3) ^ ((tid >> 3) & 3);      // = c ^ s(row), wave-invariant

    const __hip_bfloat16* aSrc0 = xb + (size_t)(mBase + r0      ) * XB_LD + g * KPAD + kc * 8;
    const __hip_bfloat16* aSrc1 = xb + (size_t)(mBase + r0 + 128) * XB_LD + g * KPAD + kc * 8;
    // N is tiled to 1024 but wb has 896 rows (819..895 zero). Clamp source rows
    // >=896 onto zero row 895: those columns are computed as 0 and never stored.
    int nrow0 = nBase + r0;        if (nrow0 > NPADW - 1) nrow0 = NPADW - 1;
    int nrow1 = nBase + r0 + 128;  if (nrow1 > NPADW - 1) nrow1 = NPADW - 1;
    const __hip_bfloat16* bSrc0 = wb + ((size_t)g * NPADW + nrow0) * KPAD + kc * 8;
    const __hip_bfloat16* bSrc1 = wb + ((size_t)g * NPADW + nrow1) * KPAD + kc * 8;

    const int dst0 = tid * 16;        // linear LDS byte offsets (wave-uniform + lane*16)
    const int dst1 = dst0 + 8192;

    // ds_read side of the swizzle: want global chunk = quad -> read chunk quad^s(row).
    // s(row) = (row>>1)&3 = (l16>>1)&3 for all frag rows (mi*16, wr*128 are 0 mod 8).
    const int cpr  = quad ^ ((l16 >> 1) & 3);
    const int aOff = (wr * 128 + l16) * 32 + cpr * 8;   // bf16 index into sA[buf]
    const int bOff = (wc * 64  + l16) * 32 + cpr * 8;

    f32x4 acc[8][4] = {};

#define STAGE(t, buf) do {                                       \
        const int koff = (t) * 32;                               \
        gld_lds16(aSrc0 + koff, (char*)sA[(buf)] + dst0);        \
        gld_lds16(aSrc1 + koff, (char*)sA[(buf)] + dst1);        \
        gld_lds16(bSrc0 + koff, (char*)sB[(buf)] + dst0);        \
        gld_lds16(bSrc1 + koff, (char*)sB[(buf)] + dst1);        \
    } while (0)

    // Prologue: 2 tiles in flight.
    STAGE(0, 0);
    STAGE(1, 1);

    for (int t = 0; t < NT; ++t) {
        // Depth-2 ring: stage tile t+2 into buf (t+2)&3. That buffer's last
        // readers (tile t-2) drained their ds_reads (lgkmcnt before MFMA) and
        // two barriers have passed since -> WAR-safe.
        if (t + 2 < NT) STAGE(t + 2, (t + 2) & 3);
        __builtin_amdgcn_sched_barrier(0);
        // Counted wait: keep the newest 2 tiles (8 gld_lds) in flight; retire
        // tile t's 4 loads (issued 2 tiles ago -> usually already landed).
        if (t + 2 < NT) {
            asm volatile("s_waitcnt vmcnt(8)" ::: "memory");
        } else if (t + 1 < NT) {
            asm volatile("s_waitcnt vmcnt(4)" ::: "memory");
        } else {
            asm volatile("s_waitcnt vmcnt(0)" ::: "memory");
        }
        __builtin_amdgcn_s_barrier();   // raw barrier: no vmcnt(0) drain
        __builtin_amdgcn_sched_barrier(0);

        const __hip_bfloat16* A = sA[t & 3];
        const __hip_bfloat16* B = sB[t & 3];
        bf16x8 a[8], b[4];
#pragma unroll
        for (int ni = 0; ni < 4; ++ni)
            b[ni] = *reinterpret_cast<const bf16x8*>(B + bOff + ni * 512);
#pragma unroll
        for (int mi = 0; mi < 8; ++mi)
            a[mi] = *reinterpret_cast<const bf16x8*>(A + aOff + mi * 512);

        __builtin_amdgcn_s_setprio(1);
#pragma unroll
        for (int mi = 0; mi < 8; ++mi)
#pragma unroll
            for (int ni = 0; ni < 4; ++ni)
                acc[mi][ni] = __builtin_amdgcn_mfma_f32_16x16x32_bf16(a[mi], b[ni], acc[mi][ni], 0, 0, 0);
        __builtin_amdgcn_s_setprio(0);
    }
#undef STAGE

    // Epilogue: D row = quad*4 + r, col = l16 (verified layout). Guard n < 819.
    const int orow0 = mBase + wr * 128 + quad * 4;
    const int ocol0 = nBase + wc * 64 + l16;
#pragma unroll
    for (int mi = 0; mi < 8; ++mi) {
#pragma unroll
        for (int ni = 0; ni < 4; ++ni) {
            const int nc = ocol0 + ni * 16;
            if (nc < BS) {
                float* op = out + (size_t)(orow0 + mi * 16) * H + (size_t)g * BS + nc;
#pragma unroll
                for (int r = 0; r < 4; ++r)
                    op[(size_t)r * H] = acc[mi][ni][r];
            }
        }
    }
}

// ---------------------------------------------------------------------------
// Fallback (workspace too small): direct fp32, one thread/output.
// ---------------------------------------------------------------------------
__global__ void fallback_kernel(const float* __restrict__ x,
                                const float* __restrict__ W,
                                float* __restrict__ out) {
    const size_t idx = (size_t)blockIdx.x * blockDim.x + threadIdx.x;
    if (idx >= (size_t)M_TOTAL * H) return;
    const int m = (int)(idx / H);
    const int o = (int)(idx % H);
    const int g = o / BS;
    const int h0 = g * BS;
    const int len = (g < NB) ? BS : 1;
    const float* xr = x + (size_t)m * H + h0;
    const float* wr = W + (size_t)o * H + h0;
    float s = 0.f;
    for (int k = 0; k < len; ++k) s += xr[k] * wr[k];
    out[idx] = s;
}

extern "C" void kernel_launch(void* const* d_in, const int* in_sizes, int n_in,
                              void* d_out, int out_size, void* d_ws, size_t ws_size,
                              hipStream_t stream) {
    const float* x = (const float*)d_in[0];
    const float* W = (const float*)d_in[1];
    float* out = (float*)d_out;

    const size_t xb_elems = (size_t)M_TOTAL * XB_LD;        // 68,157,440
    const size_t wb_elems = (size_t)NB * NPADW * KPAD;      //  3,727,360 (unchanged)
    const size_t need = (xb_elems + wb_elems) * sizeof(__hip_bfloat16);

    if (ws_size < need) {
        const size_t total = (size_t)M_TOTAL * H;
        fallback_kernel<<<(unsigned)((total + 255) / 256), 256, 0, stream>>>(x, W, out);
        return;
    }

    __hip_bfloat16* xb = (__hip_bfloat16*)d_ws;
    __hip_bfloat16* wb = xb + xb_elems;

    prep_kernel<<<PX_BLOCKS + PW_BLOCKS + LC_BLOCKS, 256, 0, stream>>>(x, W, xb, wb, out);
    gemm_kernel<<<dim3(M_TOTAL / BM, 4, NB), 512, 0, stream>>>(xb, wb, out);
}

// Round 2
// 661.865 us; speedup vs baseline: 1.0359x; 1.0009x over previous
//
#include <hip/hip_runtime.h>
#include <hip/hip_bf16.h>

// Problem constants
#define H       4096
#define BS      819        // diagonal block size
#define NB      5          // full diagonal blocks; o=h=4095 handled separately
#define KPAD    832        // K per block padded to 26*32 (13 tiles of 64)
#define NPADW   896        // packed-W rows per block (rows 819..895 are zeros)
#define M_TOTAL 16384      // 8 * 2048
#define XB_LD   (NB * KPAD) // 4160 bf16 per packed-x row
#define BM      256
#define BN      256

typedef __bf16 bf16x8 __attribute__((ext_vector_type(8)));
typedef float  f32x4  __attribute__((ext_vector_type(4)));
typedef float  f32x4u __attribute__((ext_vector_type(4), aligned(4))); // dword-aligned vector load

__device__ __forceinline__ void gld_lds16(const void* gptr, void* ldsptr) {
    __builtin_amdgcn_global_load_lds(
        (const __attribute__((address_space(1))) void*)gptr,
        (__attribute__((address_space(3))) void*)ldsptr,
        16, 0, 0);
}

// ---------------------------------------------------------------------------
// Fused prep: pack_x (8 cols/thread, 16B stores) + pack_w + last_col.
// (unchanged from round 1 — known good)
// ---------------------------------------------------------------------------
#define PX_GX     3
#define PX_BLOCKS (PX_GX * M_TOTAL)
#define PW_PER_G  ((NPADW * KPAD) / 4 / 256)
#define PW_BLOCKS (PW_PER_G * NB)
#define LC_BLOCKS (M_TOTAL / 256)

__global__ void prep_kernel(const float* __restrict__ x,
                            const float* __restrict__ W,
                            __hip_bfloat16* __restrict__ xb,
                            __hip_bfloat16* __restrict__ wb,
                            float* __restrict__ out) {
    const int bid = blockIdx.x;
    if (bid < PX_BLOCKS) {
        const int m  = bid / PX_GX;
        const int c8 = (bid % PX_GX) * 256 + threadIdx.x;
        if (c8 >= XB_LD / 8) return;
        const int j8 = c8 * 8;
        const int g  = j8 / KPAD;
        const int jj = j8 - g * KPAD;
        const float* xr = x + (size_t)m * H + g * BS;
        union { __hip_bfloat16 h[8]; uint4 u; } v;
        if (jj + 8 <= BS) {
            f32x4u f0 = *reinterpret_cast<const f32x4u*>(xr + jj);
            f32x4u f1 = *reinterpret_cast<const f32x4u*>(xr + jj + 4);
#pragma unroll
            for (int i = 0; i < 4; ++i) {
                v.h[i]     = __float2bfloat16(f0[i]);
                v.h[4 + i] = __float2bfloat16(f1[i]);
            }
        } else {
#pragma unroll
            for (int i = 0; i < 8; ++i) {
                float f = (jj + i < BS) ? xr[jj + i] : 0.f;
                v.h[i] = __float2bfloat16(f);
            }
        }
        *reinterpret_cast<uint4*>(xb + (size_t)m * XB_LD + j8) = v.u;
    } else if (bid < PX_BLOCKS + PW_BLOCKS) {
        const int b   = bid - PX_BLOCKS;
        const int g   = b / PW_PER_G;
        const int t4  = (b - g * PW_PER_G) * 256 + threadIdx.x;
        const int idx = t4 * 4;
        const int n = idx / KPAD;
        const int k = idx - n * KPAD;
        union { __hip_bfloat16 h[4]; uint2 u; } v;
        if (n < BS && k + 4 <= BS) {
            f32x4u f = *reinterpret_cast<const f32x4u*>(W + (size_t)(g * BS + n) * H + g * BS + k);
#pragma unroll
            for (int i = 0; i < 4; ++i) v.h[i] = __float2bfloat16(f[i]);
        } else {
#pragma unroll
            for (int i = 0; i < 4; ++i) {
                float f = 0.f;
                if (n < BS && k + i < BS) f = W[(size_t)(g * BS + n) * H + g * BS + k + i];
                v.h[i] = __float2bfloat16(f);
            }
        }
        *reinterpret_cast<uint2*>(wb + ((size_t)g * NPADW + n) * KPAD + k) = v.u;
    } else {
        const int m = (bid - PX_BLOCKS - PW_BLOCKS) * 256 + threadIdx.x;
        if (m >= M_TOTAL) return;
        const float w = W[(size_t)4095 * H + 4095];
        out[(size_t)m * H + 4095] = x[(size_t)m * H + 4095] * w;
    }
}

// ---------------------------------------------------------------------------
// Block-diagonal bf16 GEMM — 8-phase schedule (T3+T4+T2+T5):
//   256x256 tile, 512 thr = 8 waves (2M x 4N), wave-tile 128x64, BK=64,
//   LDS = 2 bufs x 2 K-half panels x {A,B} x [256][32] bf16 = 128 KiB.
//   Phase = {4|8 ds_read_b128, 1 half-tile stage (2 gld_lds), barrier,
//            16 MFMA @setprio(1), vmcnt(8), barrier}. 8 phases / 2 K-tiles.
//   Stage->first-read gap >= 5 phases; per-phase vmcnt(8) == stage(psi-4)
//   landed -> race-free, never drains vmcnt in the main loop.
//   Swizzle (64B panel rows): chunk cl = cg ^ ((row>>1)&3), applied on the
//   pre-swizzled global SOURCE (linear gld_lds dest) + same XOR on reads.
// ---------------------------------------------------------------------------
__global__ __launch_bounds__(512, 2)
void gemm_kernel(const __hip_bfloat16* __restrict__ xb,
                 const __hip_bfloat16* __restrict__ wb,
                 float* __restrict__ out) {
    __shared__ __hip_bfloat16 sA[2][2][256 * 32];   // [buf][khalf][row*32+k] 4x16KB
    __shared__ __hip_bfloat16 sB[2][2][256 * 32];   // 4x16KB -> 128 KiB total

    const int tid  = threadIdx.x;
    const int lane = tid & 63;
    const int wid  = tid >> 6;        // 0..7
    const int wr   = wid >> 2;        // 0..1: wave row (128 rows)
    const int wc   = wid & 3;         // 0..3: wave col (64 cols)
    const int l16  = lane & 15;
    const int quad = lane >> 4;

    const int mBase = blockIdx.x * BM;
    const int nBase = blockIdx.y * BN;
    const int g     = blockIdx.z;

    // ---- staging addressing: half-tile = one [256][32] panel = 16 KB = 2 rounds
    // linear LDS dest byte L*16: row = L>>2, chunk cl = L&3 (panel rows = 64 B)
    // source chunk cg = cl ^ ((row>>1)&3)  (involution)
    const int srow = tid >> 2;                        // round-0 rows 0..127 (+128 rnd 1)
    const int cg   = (tid & 3) ^ ((tid >> 3) & 3);
    const __hip_bfloat16* aS0 = xb + (size_t)(mBase + srow) * XB_LD + g * KPAD + cg * 8;
    const __hip_bfloat16* aS1 = aS0 + (size_t)128 * XB_LD;
    int nr0 = nBase + srow;        if (nr0 > NPADW - 1) nr0 = NPADW - 1; // clamp to zero row
    int nr1 = nBase + srow + 128;  if (nr1 > NPADW - 1) nr1 = NPADW - 1;
    const __hip_bfloat16* bS0 = wb + ((size_t)g * NPADW + nr0) * KPAD + cg * 8;
    const __hip_bfloat16* bS1 = wb + ((size_t)g * NPADW + nr1) * KPAD + cg * 8;
    const int dst0 = tid * 16;
    const int dst1 = dst0 + 8192;

#define STAGE_A(BUF, u, kh) do {                                         \
        gld_lds16(aS0 + (u) * 64 + (kh) * 32, (char*)sA[BUF][kh] + dst0);\
        gld_lds16(aS1 + (u) * 64 + (kh) * 32, (char*)sA[BUF][kh] + dst1);\
    } while (0)
#define STAGE_B(BUF, u, kh) do {                                         \
        gld_lds16(bS0 + (u) * 64 + (kh) * 32, (char*)sB[BUF][kh] + dst0);\
        gld_lds16(bS1 + (u) * 64 + (kh) * 32, (char*)sB[BUF][kh] + dst1);\
    } while (0)

    // ---- read-side addressing (byte offsets into a panel)
    const int cl16 = (quad ^ ((l16 >> 1) & 3)) * 16;          // swizzled 16B chunk
    const int aRd  = (wr * 128 + l16) * 64 + cl16;            // + mi*1024
    const int bRd  = (wc * 64  + l16) * 64 + cl16;            // + ni*1024

    f32x4 acc[8][4] = {};
    bf16x8 b0, b1, b2, b3;          // persist across the H0->H1 phase pair

#define MFMA1(MI, A_) do {                                                           \
        acc[MI][0] = __builtin_amdgcn_mfma_f32_16x16x32_bf16(A_, b0, acc[MI][0],0,0,0);\
        acc[MI][1] = __builtin_amdgcn_mfma_f32_16x16x32_bf16(A_, b1, acc[MI][1],0,0,0);\
        acc[MI][2] = __builtin_amdgcn_mfma_f32_16x16x32_bf16(A_, b2, acc[MI][2],0,0,0);\
        acc[MI][3] = __builtin_amdgcn_mfma_f32_16x16x32_bf16(A_, b3, acc[MI][3],0,0,0);\
    } while (0)

    // One phase: compute tile in BUF, K-half KK, mi-half HH (literal 0/1).
    // STG = staging statement (may be empty), VM = vmcnt immediate (string).
    #define PH(BUF, KK, HH, STG, VM) do {                                            \
        bf16x8 a0_, a1_, a2_, a3_;                                                   \
        {   const char* p_ = (const char*)sA[BUF][KK] + aRd + (HH) * 4096;           \
            a0_ = *(const bf16x8*)(p_);                                              \
            a1_ = *(const bf16x8*)(p_ + 1024);                                       \
            a2_ = *(const bf16x8*)(p_ + 2048);                                       \
            a3_ = *(const bf16x8*)(p_ + 3072); }                                     \
        if ((HH) == 0) {                                                             \
            const char* q_ = (const char*)sB[BUF][KK] + bRd;                         \
            b0 = *(const bf16x8*)(q_);                                               \
            b1 = *(const bf16x8*)(q_ + 1024);                                        \
            b2 = *(const bf16x8*)(q_ + 2048);                                        \
            b3 = *(const bf16x8*)(q_ + 3072); }                                      \
        STG;                                                                         \
        __builtin_amdgcn_s_barrier();                                                \
        __builtin_amdgcn_s_setprio(1);                                               \
        MFMA1((HH) * 4 + 0, a0_);                                                    \
        MFMA1((HH) * 4 + 1, a1_);                                                    \
        MFMA1((HH) * 4 + 2, a2_);                                                    \
        MFMA1((HH) * 4 + 3, a3_);                                                    \
        __builtin_amdgcn_s_setprio(0);                                               \
        asm volatile("s_waitcnt vmcnt(" VM ")" ::: "memory");                        \
        __builtin_amdgcn_s_barrier();                                                \
    } while (0)

    // ---- prologue: 6 half-tiles (order matters for the vmcnt ledger)
    STAGE_A(0, 0, 0);   // #1  tile0 A-kh0
    STAGE_B(0, 0, 0);   // #2  tile0 B-kh0
    STAGE_A(0, 0, 1);   // #3  tile0 A-kh1
    STAGE_B(0, 0, 1);   // #4  tile0 B-kh1
    STAGE_A(1, 1, 0);   // #5  tile1 A-kh0
    STAGE_B(1, 1, 0);   // #6  tile1 B-kh0
    asm volatile("s_waitcnt vmcnt(8)" ::: "memory");   // #1,#2 landed
    __builtin_amdgcn_s_barrier();

    // ---- main loop: iterations over tile pairs (2i, 2i+1); bufs are static 0/1
    for (int i = 0; i < 5; ++i) {
        const int t1 = 2 * i + 1, t2 = 2 * i + 2, t3 = 2 * i + 3;
        PH(0, 0, 0, STAGE_A(1, t1, 1), "8");   // stage A-kh1(t+1) -> read P7
        PH(0, 0, 1, STAGE_B(1, t1, 1), "8");   // stage B-kh1(t+1) -> read P7
        PH(0, 1, 0, STAGE_A(0, t2, 0), "8");   // stage A-kh0(t+2) -> read next P1
        PH(0, 1, 1, STAGE_B(0, t2, 0), "8");
        PH(1, 0, 0, STAGE_A(0, t2, 1), "8");   // stage A-kh1(t+2) -> read next P3
        PH(1, 0, 1, STAGE_B(0, t2, 1), "8");
        PH(1, 1, 0, STAGE_A(1, t3, 0), "8");   // stage A-kh0(t+3) -> read next P5
        PH(1, 1, 1, STAGE_B(1, t3, 0), "8");
    }

    // ---- peeled iteration: tiles 10,11; stage tile 12 only (no tile 13)
    PH(0, 0, 0, STAGE_A(1, 11, 1), "8");
    PH(0, 0, 1, STAGE_B(1, 11, 1), "8");
    PH(0, 1, 0, STAGE_A(0, 12, 0), "8");
    PH(0, 1, 1, STAGE_B(0, 12, 0), "8");
    PH(1, 0, 0, STAGE_A(0, 12, 1), "8");
    PH(1, 0, 1, STAGE_B(0, 12, 1), "8");
    PH(1, 1, 0, { }, "8");
    PH(1, 1, 1, { }, "4");                     // kh0(12) landed; kh1(12) may fly

    // ---- epilogue: tile 12 (buf0); vmcnt(0) before its kh1 reads
    PH(0, 0, 0, { }, "4");
    PH(0, 0, 1, { }, "0");                     // after this barrier kh1(12) is safe
    PH(0, 1, 0, { }, "0");
    PH(0, 1, 1, { }, "0");

#undef PH
#undef MFMA1
#undef STAGE_A
#undef STAGE_B

    // ---- C write: D row = quad*4 + r, col = l16 (layout verified in round 1)
    const int orow0 = mBase + wr * 128 + quad * 4;
    const int ocol0 = nBase + wc * 64 + l16;
#pragma unroll
    for (int mi = 0; mi < 8; ++mi) {
#pragma unroll
        for (int ni = 0; ni < 4; ++ni) {
            const int nc = ocol0 + ni * 16;
            if (nc < BS) {
                float* op = out + (size_t)(orow0 + mi * 16) * H + (size_t)g * BS + nc;
#pragma unroll
                for (int r = 0; r < 4; ++r)
                    op[(size_t)r * H] = acc[mi][ni][r];
            }
        }
    }
}

// ---------------------------------------------------------------------------
// Fallback (workspace too small): direct fp32, one thread/output.
// ---------------------------------------------------------------------------
__global__ void fallback_kernel(const float* __restrict__ x,
                                const float* __restrict__ W,
                                float* __restrict__ out) {
    const size_t idx = (size_t)blockIdx.x * blockDim.x + threadIdx.x;
    if (idx >= (size_t)M_TOTAL * H) return;
    const int m = (int)(idx / H);
    const int o = (int)(idx % H);
    const int g = o / BS;
    const int h0 = g * BS;
    const int len = (g < NB) ? BS : 1;
    const float* xr = x + (size_t)m * H + h0;
    const float* wr = W + (size_t)o * H + h0;
    float s = 0.f;
    for (int k = 0; k < len; ++k) s += xr[k] * wr[k];
    out[idx] = s;
}

extern "C" void kernel_launch(void* const* d_in, const int* in_sizes, int n_in,
                              void* d_out, int out_size, void* d_ws, size_t ws_size,
                              hipStream_t stream) {
    const float* x = (const float*)d_in[0];
    const float* W = (const float*)d_in[1];
    float* out = (float*)d_out;

    const size_t xb_elems = (size_t)M_TOTAL * XB_LD;
    const size_t wb_elems = (size_t)NB * NPADW * KPAD;
    const size_t need = (xb_elems + wb_elems) * sizeof(__hip_bfloat16);

    if (ws_size < need) {
        const size_t total = (size_t)M_TOTAL * H;
        fallback_kernel<<<(unsigned)((total + 255) / 256), 256, 0, stream>>>(x, W, out);
        return;
    }

    __hip_bfloat16* xb = (__hip_bfloat16*)d_ws;
    __hip_bfloat16* wb = xb + xb_elems;

    prep_kernel<<<PX_BLOCKS + PW_BLOCKS + LC_BLOCKS, 256, 0, stream>>>(x, W, xb, wb, out);
    gemm_kernel<<<dim3(M_TOTAL / BM, 4, NB), 512, 0, stream>>>(xb, wb, out);
}